// Round 8
// baseline (516.569 us; speedup 1.0000x reference)
//
#include <hip/hip_runtime.h>
#include <hip/hip_fp16.h>

#define IN_DIM 256
#define HID_DIM 128
#define OUT_DIM 64

typedef short s8v __attribute__((ext_vector_type(8)));
typedef float f32x4 __attribute__((ext_vector_type(4)));

// ---------------- bf16 split helpers ----------------

__device__ __forceinline__ unsigned short bf16_rne(float f) {
    unsigned int u = __float_as_uint(f);
    u += 0x7FFFu + ((u >> 16) & 1u);
    return (unsigned short)(u >> 16);
}
__device__ __forceinline__ float bfbits_to_f(unsigned short h) {
    return __uint_as_float(((unsigned int)h) << 16);
}
__device__ __forceinline__ void cvt_split4(float4 f, uint2& hv, uint2& lv) {
    unsigned short h0 = bf16_rne(f.x), h1 = bf16_rne(f.y);
    unsigned short h2 = bf16_rne(f.z), h3 = bf16_rne(f.w);
    unsigned short l0 = bf16_rne(f.x - bfbits_to_f(h0));
    unsigned short l1 = bf16_rne(f.y - bfbits_to_f(h1));
    unsigned short l2 = bf16_rne(f.z - bfbits_to_f(h2));
    unsigned short l3 = bf16_rne(f.w - bfbits_to_f(h3));
    hv.x = (unsigned int)h0 | ((unsigned int)h1 << 16);
    hv.y = (unsigned int)h2 | ((unsigned int)h3 << 16);
    lv.x = (unsigned int)l0 | ((unsigned int)l1 << 16);
    lv.y = (unsigned int)l2 | ((unsigned int)l3 << 16);
}

union frag_u { uint4 u; s8v v; };

__global__ __launch_bounds__(256) void wsplit_kernel(const float* __restrict__ W,
        unsigned short* __restrict__ wth, unsigned short* __restrict__ wtl,
        int K, int NCOL) {
    int idx = blockIdx.x * 256 + threadIdx.x;
    if (idx < K * NCOL) {
        int k = idx / NCOL, nn = idx % NCOL;
        float f = W[idx];
        unsigned short h = bf16_rne(f);
        unsigned short l = bf16_rne(f - bfbits_to_f(h));
        wth[nn * K + k] = h;
        wtl[nn * K + k] = l;
    }
}

// ---------------- preprocessing ----------------
// packed[i]: bits [63:40] = edge count, bits [39:0] = fixed-point (2^-24) sum of w.

#define FPSCALE 16777216.0f
#define FPMASK  ((1ULL << 40) - 1)

__global__ __launch_bounds__(256) void init_kernel(unsigned long long* packed, int n) {
    int i = blockIdx.x * 256 + threadIdx.x;
    if (i < n) packed[i] = (1ULL << 24);      // deg = 1.0 (self-loop), cnt = 0
}

__global__ __launch_bounds__(256) void deg_cnt_kernel(const int* __restrict__ col,
        const float* __restrict__ w, unsigned long long* packed,
        int* __restrict__ arr, int e) {
    int i = blockIdx.x * 256 + threadIdx.x;
    if (i < e) {
        unsigned long long v = (1ULL << 40) |
            (unsigned long long)(w[i] * FPSCALE + 0.5f);
        unsigned long long old = atomicAdd(&packed[col[i]], v);
        arr[i] = (int)(old >> 40);
    }
}

__global__ __launch_bounds__(256) void dinv_kernel(const unsigned long long* __restrict__ packed,
        float* __restrict__ dinv, int* __restrict__ cnt, int n) {
    int i = blockIdx.x * 256 + threadIdx.x;
    if (i < n) {
        unsigned long long p = packed[i];
        float d = (float)(p & FPMASK) * (1.0f / FPSCALE);
        dinv[i] = d > 0.0f ? rsqrtf(d) : 0.0f;
        cnt[i] = (int)(p >> 40);
    }
}

// ---- hierarchical exclusive scan ----

__global__ __launch_bounds__(256) void scan1_kernel(const int* __restrict__ cnt,
        int* __restrict__ bsum, int n) {
    int t = threadIdx.x;
    int base = blockIdx.x * 1024 + t * 4;
    int s = 0;
    if (base + 3 < n) {
        int4 v = *(const int4*)(cnt + base);
        s = v.x + v.y + v.z + v.w;
    } else {
        for (int i = 0; i < 4; i++) if (base + i < n) s += cnt[base + i];
    }
    __shared__ int sm[256];
    sm[t] = s;
    __syncthreads();
    for (int d = 1; d < 256; d <<= 1) {
        int v = (t >= d) ? sm[t - d] : 0;
        __syncthreads();
        sm[t] += v;
        __syncthreads();
    }
    if (t == 255) bsum[blockIdx.x] = sm[255];
}

__global__ __launch_bounds__(1024) void scan2_kernel(int* bsum, int* total_out, int nb) {
    __shared__ int sm[1024];
    int t = threadIdx.x;
    int v = (t < nb) ? bsum[t] : 0;
    sm[t] = v;
    __syncthreads();
    for (int d = 1; d < 1024; d <<= 1) {
        int u = (t >= d) ? sm[t - d] : 0;
        __syncthreads();
        sm[t] += u;
        __syncthreads();
    }
    int ex = (t == 0) ? 0 : sm[t - 1];
    if (t < nb) bsum[t] = ex;
    if (t == nb - 1) *total_out = sm[t];
}

__global__ __launch_bounds__(256) void scan3_kernel(const int* __restrict__ cnt,
        const int* __restrict__ bsum, int* __restrict__ offsets, int n) {
    int t = threadIdx.x;
    int base = blockIdx.x * 1024 + t * 4;
    int a[4] = {0, 0, 0, 0};
    if (base + 3 < n) {
        int4 v = *(const int4*)(cnt + base);
        a[0] = v.x; a[1] = v.y; a[2] = v.z; a[3] = v.w;
    } else {
        for (int i = 0; i < 4; i++) if (base + i < n) a[i] = cnt[base + i];
    }
    int s = a[0] + a[1] + a[2] + a[3];
    __shared__ int sm[256];
    sm[t] = s;
    __syncthreads();
    for (int d = 1; d < 256; d <<= 1) {
        int u = (t >= d) ? sm[t - d] : 0;
        __syncthreads();
        sm[t] += u;
        __syncthreads();
    }
    int pre = bsum[blockIdx.x] + ((t == 0) ? 0 : sm[t - 1]);
    int o0 = pre, o1 = o0 + a[0], o2 = o1 + a[1], o3 = o2 + a[2];
    if (base + 3 < n) {
        *(int4*)(offsets + base) = make_int4(o0, o1, o2, o3);
    } else {
        int o[4] = {o0, o1, o2, o3};
        for (int i = 0; i < 4; i++) if (base + i < n) offsets[base + i] = o[i];
    }
}

// CSC entry: int2{ src_row, float_bits(w) }; slot = offsets[col] + arrival index.

__global__ __launch_bounds__(256) void fill_csc_kernel(const int* __restrict__ row,
        const int* __restrict__ col, const float* __restrict__ w,
        const int* __restrict__ offsets, const int* __restrict__ arr,
        int2* __restrict__ csc, int e) {
    int i = blockIdx.x * 256 + threadIdx.x;
    if (i < e) {
        int c = col[i];
        int p = offsets[c] + arr[i];
        csc[p] = make_int2(row[i], __float_as_int(w[i]));
    }
}

// ---------------- direct-load MFMA split-bf16 GEMM (no LDS, no barriers) ------
// Each lane loads its A fragment straight from x (fp32, split in regs) and its
// B fragment straight from the pre-transposed bf16 W^T (L2-resident). Waves are
// fully independent -> latency hidden by occupancy, zero sync stalls.

template<int K, int NCOL>
__global__ __launch_bounds__(256) void gemm_direct_kernel(
        const float* __restrict__ x, const unsigned short* __restrict__ wth,
        const unsigned short* __restrict__ wtl, const float* __restrict__ dinv,
        __half* __restrict__ out, int n) {
    constexpr int NT = NCOL / 16;
    constexpr int NCH = K / 32;
    int t = threadIdx.x;
    int wave = t >> 6, lane = t & 63, quad = lane >> 4, r16 = lane & 15;
    long rowBase = (long)blockIdx.x * 128 + wave * 32;
    long m0 = rowBase + r16;      if (m0 > n - 1) m0 = n - 1;
    long m1 = rowBase + 16 + r16; if (m1 > n - 1) m1 = n - 1;

    f32x4 acc[2][NT];
#pragma unroll
    for (int mi = 0; mi < 2; mi++)
#pragma unroll
        for (int nt = 0; nt < NT; nt++) acc[mi][nt] = (f32x4)0.0f;

    const float* xr0 = x + m0 * K + quad * 8;
    const float* xr1 = x + m1 * K + quad * 8;

    for (int kc = 0; kc < NCH; kc++) {
        // A fragments: 8 consecutive fp32 per row, split to bf16 hi/lo in regs
        float4 a00 = *(const float4*)(xr0 + kc * 32);
        float4 a01 = *(const float4*)(xr0 + kc * 32 + 4);
        float4 a10 = *(const float4*)(xr1 + kc * 32);
        float4 a11 = *(const float4*)(xr1 + kc * 32 + 4);
        frag_u ah0, al0, ah1, al1;
        uint2 h0, l0, h1, l1;
        cvt_split4(a00, h0, l0); cvt_split4(a01, h1, l1);
        ah0.u = make_uint4(h0.x, h0.y, h1.x, h1.y);
        al0.u = make_uint4(l0.x, l0.y, l1.x, l1.y);
        cvt_split4(a10, h0, l0); cvt_split4(a11, h1, l1);
        ah1.u = make_uint4(h0.x, h0.y, h1.x, h1.y);
        al1.u = make_uint4(l0.x, l0.y, l1.x, l1.y);

        const unsigned short* bbase = wth + (size_t)r16 * K + kc * 32 + quad * 8;
        const unsigned short* lbase = wtl + (size_t)r16 * K + kc * 32 + quad * 8;
#pragma unroll
        for (int nt = 0; nt < NT; nt++) {
            s8v bh = *(const s8v*)(bbase + (size_t)nt * 16 * K);
            s8v bl = *(const s8v*)(lbase + (size_t)nt * 16 * K);
            acc[0][nt] = __builtin_amdgcn_mfma_f32_16x16x32_bf16(ah0.v, bh, acc[0][nt], 0, 0, 0);
            acc[0][nt] = __builtin_amdgcn_mfma_f32_16x16x32_bf16(al0.v, bh, acc[0][nt], 0, 0, 0);
            acc[0][nt] = __builtin_amdgcn_mfma_f32_16x16x32_bf16(ah0.v, bl, acc[0][nt], 0, 0, 0);
            acc[1][nt] = __builtin_amdgcn_mfma_f32_16x16x32_bf16(ah1.v, bh, acc[1][nt], 0, 0, 0);
            acc[1][nt] = __builtin_amdgcn_mfma_f32_16x16x32_bf16(al1.v, bh, acc[1][nt], 0, 0, 0);
            acc[1][nt] = __builtin_amdgcn_mfma_f32_16x16x32_bf16(ah1.v, bl, acc[1][nt], 0, 0, 0);
        }
    }
    // epilogue: C/D layout col=r16, row=quad*4+i; scale row by dinv
#pragma unroll
    for (int mi = 0; mi < 2; mi++) {
        long gr0 = rowBase + mi * 16 + quad * 4;
#pragma unroll
        for (int nt = 0; nt < NT; nt++) {
            f32x4 d = acc[mi][nt];
#pragma unroll
            for (int i = 0; i < 4; i++) {
                long gr = gr0 + i;
                if (gr < n) out[gr * NCOL + nt * 16 + r16] =
                    __float2half(d[i] * dinv[gr]);
            }
        }
    }
}

// ---------------- fp16 gather accumulate helpers ----------------

__device__ __forceinline__ void acc8(float* a, uint4 raw, float w) {
    __half2* hp = (__half2*)&raw;
    float2 f0 = __half22float2(hp[0]);
    float2 f1 = __half22float2(hp[1]);
    float2 f2 = __half22float2(hp[2]);
    float2 f3 = __half22float2(hp[3]);
    a[0] += w * f0.x; a[1] += w * f0.y; a[2] += w * f1.x; a[3] += w * f1.y;
    a[4] += w * f2.x; a[5] += w * f2.y; a[6] += w * f3.x; a[7] += w * f3.y;
}

__device__ __forceinline__ void acc4h(float* a, uint2 raw, float w) {
    __half2* hp = (__half2*)&raw;
    float2 f0 = __half22float2(hp[0]);
    float2 f1 = __half22float2(hp[1]);
    a[0] += w * f0.x; a[1] += w * f0.y; a[2] += w * f1.x; a[3] += w * f1.y;
}

// ---------------- aggregation layer 1 (D=128 fp16 in, fp32 out, +bias, relu) ----

__global__ __launch_bounds__(256) void agg1_kernel(const __half* __restrict__ h,
        const float* __restrict__ dinv, const int* __restrict__ offsets,
        const int2* __restrict__ csc, const float* __restrict__ b,
        float* __restrict__ out, int n) {
    int t = threadIdx.x;
    int lane = t & 63;
    int strm = lane >> 4;            // 0..3
    int li = lane & 15;              // half8 index in row (16*8 = 128 dims)
    int node = blockIdx.x * 4 + (t >> 6);
    if (node >= n) return;

    float a0[8] = {0,0,0,0,0,0,0,0};
    float a1[8] = {0,0,0,0,0,0,0,0};
    int s = offsets[node], e = offsets[node + 1];

    if (strm == 0) {                 // self-loop: weight 1 * h'[node]
        uint4 raw = ((const uint4*)(h + (long)node * HID_DIM))[li];
        acc8(a0, raw, 1.0f);
    }

    int p = s + strm;
    for (; p + 4 < e; p += 8) {
        int2 e0 = csc[p], e1 = csc[p + 4];
        uint4 r0 = ((const uint4*)(h + (long)e0.x * HID_DIM))[li];
        uint4 r1 = ((const uint4*)(h + (long)e1.x * HID_DIM))[li];
        acc8(a0, r0, __int_as_float(e0.y));
        acc8(a1, r1, __int_as_float(e1.y));
    }
    if (p < e) {
        int2 e0 = csc[p];
        uint4 r0 = ((const uint4*)(h + (long)e0.x * HID_DIM))[li];
        acc8(a0, r0, __int_as_float(e0.y));
    }
#pragma unroll
    for (int j = 0; j < 8; j++) a0[j] += a1[j];
#pragma unroll
    for (int j = 0; j < 8; j++) a0[j] += __shfl_down(a0[j], 32);
#pragma unroll
    for (int j = 0; j < 8; j++) a0[j] += __shfl_down(a0[j], 16);
    if (strm == 0) {
        float di = dinv[node];
        float4 bv0 = ((const float4*)b)[li * 2];
        float4 bv1 = ((const float4*)b)[li * 2 + 1];
        float4 o0 = make_float4(fmaxf(di * a0[0] + bv0.x, 0.f), fmaxf(di * a0[1] + bv0.y, 0.f),
                                fmaxf(di * a0[2] + bv0.z, 0.f), fmaxf(di * a0[3] + bv0.w, 0.f));
        float4 o1 = make_float4(fmaxf(di * a0[4] + bv1.x, 0.f), fmaxf(di * a0[5] + bv1.y, 0.f),
                                fmaxf(di * a0[6] + bv1.z, 0.f), fmaxf(di * a0[7] + bv1.w, 0.f));
        float4* dst = (float4*)(out + (long)node * HID_DIM);
        dst[li * 2] = o0;
        dst[li * 2 + 1] = o1;
    }
}

// ---------------- aggregation layer 2 (D=64 fp16 in, fp32 out, +bias) ----------

__global__ __launch_bounds__(256) void agg2_kernel(const __half* __restrict__ h,
        const float* __restrict__ dinv, const int* __restrict__ offsets,
        const int2* __restrict__ csc, const float* __restrict__ b,
        float* __restrict__ out, int n) {
    int t = threadIdx.x;
    int lane = t & 63;
    int strm = lane >> 4;            // 0..3
    int li = lane & 15;              // half4 index in row (16*4 = 64 dims)
    int node = blockIdx.x * 4 + (t >> 6);
    if (node >= n) return;

    float a0[4] = {0,0,0,0};
    float a1[4] = {0,0,0,0};
    int s = offsets[node], e = offsets[node + 1];

    if (strm == 0) {
        uint2 raw = ((const uint2*)(h + (long)node * OUT_DIM))[li];
        acc4h(a0, raw, 1.0f);
    }

    int p = s + strm;
    for (; p + 4 < e; p += 8) {
        int2 e0 = csc[p], e1 = csc[p + 4];
        uint2 r0 = ((const uint2*)(h + (long)e0.x * OUT_DIM))[li];
        uint2 r1 = ((const uint2*)(h + (long)e1.x * OUT_DIM))[li];
        acc4h(a0, r0, __int_as_float(e0.y));
        acc4h(a1, r1, __int_as_float(e1.y));
    }
    if (p < e) {
        int2 e0 = csc[p];
        uint2 r0 = ((const uint2*)(h + (long)e0.x * OUT_DIM))[li];
        acc4h(a0, r0, __int_as_float(e0.y));
    }
#pragma unroll
    for (int j = 0; j < 4; j++) a0[j] += a1[j];
#pragma unroll
    for (int j = 0; j < 4; j++) a0[j] += __shfl_down(a0[j], 32);
#pragma unroll
    for (int j = 0; j < 4; j++) a0[j] += __shfl_down(a0[j], 16);
    if (strm == 0) {
        float di = dinv[node];
        float4 bv = ((const float4*)b)[li];
        ((float4*)(out + (long)node * OUT_DIM))[li] =
            make_float4(di * a0[0] + bv.x, di * a0[1] + bv.y,
                        di * a0[2] + bv.z, di * a0[3] + bv.w);
    }
}

// ---------------- launch ----------------

extern "C" void kernel_launch(void* const* d_in, const int* in_sizes, int n_in,
                              void* d_out, int out_size, void* d_ws, size_t ws_size,
                              hipStream_t stream) {
    const float* x  = (const float*)d_in[0];
    const int*   ei = (const int*)d_in[1];
    const float* w  = (const float*)d_in[2];
    const float* W1 = (const float*)d_in[3];
    const float* b1 = (const float*)d_in[4];
    const float* W2 = (const float*)d_in[5];
    const float* b2 = (const float*)d_in[6];
    float* out = (float*)d_out;

    int N = in_sizes[0] / IN_DIM;       // 100000
    int E = in_sizes[2];                // 1600000
    const int* row = ei;
    const int* col = ei + E;

    char* base = (char*)d_ws;
    size_t off = 0;
    auto alloc = [&](size_t bytes) -> void* {
        void* p = base + off;
        off += (bytes + 255) & ~(size_t)255;
        return p;
    };
    unsigned long long* packed = (unsigned long long*)alloc((size_t)N * 8);
    float* dinv     = (float*)alloc((size_t)N * 4);
    int*   cnt      = (int*)  alloc((size_t)N * 4);
    int*   offsets  = (int*)  alloc((size_t)(N + 1) * 4);
    int*   arr      = (int*)  alloc((size_t)E * 4);
    int*   bsum     = (int*)  alloc((size_t)1024 * 4);
    int2*  csc      = (int2*) alloc((size_t)E * 8);
    __half* h       = (__half*)alloc((size_t)N * HID_DIM * 2);  // fp16; reused for h2
    float* hagg     = (float*)alloc((size_t)N * HID_DIM * 4);
    unsigned short* wt1h = (unsigned short*)alloc((size_t)IN_DIM * HID_DIM * 2);
    unsigned short* wt1l = (unsigned short*)alloc((size_t)IN_DIM * HID_DIM * 2);
    unsigned short* wt2h = (unsigned short*)alloc((size_t)HID_DIM * OUT_DIM * 2);
    unsigned short* wt2l = (unsigned short*)alloc((size_t)HID_DIM * OUT_DIM * 2);

    int gN = (N + 255) / 256;
    int gE = (E + 255) / 256;
    int gGemm = (N + 127) / 128;
    int gAgg = (N + 3) / 4;
    int nbScan = (N + 1023) / 1024;

    wsplit_kernel<<<(IN_DIM * HID_DIM + 255) / 256, 256, 0, stream>>>(
        W1, wt1h, wt1l, IN_DIM, HID_DIM);
    wsplit_kernel<<<(HID_DIM * OUT_DIM + 255) / 256, 256, 0, stream>>>(
        W2, wt2h, wt2l, HID_DIM, OUT_DIM);
    init_kernel<<<gN, 256, 0, stream>>>(packed, N);
    deg_cnt_kernel<<<gE, 256, 0, stream>>>(col, w, packed, arr, E);
    dinv_kernel<<<gN, 256, 0, stream>>>(packed, dinv, cnt, N);
    scan1_kernel<<<nbScan, 256, 0, stream>>>(cnt, bsum, N);
    scan2_kernel<<<1, 1024, 0, stream>>>(bsum, offsets + N, nbScan);
    scan3_kernel<<<nbScan, 256, 0, stream>>>(cnt, bsum, offsets, N);
    fill_csc_kernel<<<gE, 256, 0, stream>>>(row, col, w, offsets, arr, csc, E);
    gemm_direct_kernel<IN_DIM, HID_DIM><<<gGemm, 256, 0, stream>>>(x, wt1h, wt1l, dinv, h, N);
    agg1_kernel<<<gAgg, 256, 0, stream>>>(h, dinv, offsets, csc, b1, hagg, N);
    gemm_direct_kernel<HID_DIM, OUT_DIM><<<gGemm, 256, 0, stream>>>(hagg, wt2h, wt2l, dinv, h, N);
    agg2_kernel<<<gAgg, 256, 0, stream>>>(h, dinv, offsets, csc, b2, out, N);
}